// Round 6
// baseline (124.298 us; speedup 1.0000x reference)
//
#include <hip/hip_runtime.h>

typedef __attribute__((__ext_vector_type__(8))) _Float16 f16x8;
typedef __attribute__((__ext_vector_type__(4))) float f32x4;
typedef __attribute__((__ext_vector_type__(4))) int i32x4;

#define HW 56
#define HW2 3136
#define CIN 128
#define COUT 256
#define NB 32
#define NPIX 100352  // 32*3136
#define PH 58        // padded spatial dim (1-px halo)

static __device__ __forceinline__ unsigned short f2h(float f) {
  _Float16 h = (_Float16)f;
  return __builtin_bit_cast(unsigned short, h);
}

#define GLD_LDS16(g, l)                                          \
  __builtin_amdgcn_global_load_lds(                              \
      (const __attribute__((address_space(1))) void*)(g),        \
      (__attribute__((address_space(3))) void*)(l), 16, 0, 0)

// ---- zero the 1-pixel halo of x_pad ----
__global__ __launch_bounds__(256) void zero_halo(unsigned short* __restrict__ xp) {
  int t = blockIdx.x * 256 + threadIdx.x;  // 32*228*16 threads
  int ck = t & 15;                          // 16B chunk in 256B pixel
  int pi = t >> 4;
  int b = pi / 228, r = pi - b * 228;
  int h, w;
  if (r < 58) { h = 0; w = r; }
  else if (r < 116) { h = 57; w = r - 58; }
  else { int q = r - 116; h = 1 + (q >> 1); w = (q & 1) * 57; }
  size_t off = (((size_t)(b * PH + h) * PH + w) << 8) + (ck << 4);
  *reinterpret_cast<i32x4*>((char*)xp + off) = (i32x4){0, 0, 0, 0};
}

// ---- prep_x: x NCHW f32 -> x_pad [32][58][58][128] f16 (interior), plus channel-sum xs ----
__global__ __launch_bounds__(256) void prep_x(const float* __restrict__ x,
                                              unsigned short* __restrict__ xp,
                                              float* __restrict__ xs) {
  __shared__ float tile[CIN * 57];  // [c][w], stride 57 kills bank conflicts
  const int bh = blockIdx.x;        // b*56 + h
  const float* src = x + (size_t)(bh / HW) * CIN * HW2 + (size_t)(bh % HW) * HW;
  for (int idx = threadIdx.x; idx < CIN * HW; idx += 256) {
    int c = idx / HW, w = idx - c * HW;
    tile[c * 57 + w] = src[(size_t)c * HW2 + w];
  }
  __syncthreads();
  unsigned short* dst =
      xp + (((size_t)(bh / HW) * PH + (bh % HW) + 1) * PH + 1) * CIN;
  for (int idx = threadIdx.x; idx < HW * (CIN / 2); idx += 256) {
    int w = idx >> 6;         // pixel within row
    int c = (idx & 63) << 1;  // channel pair
    unsigned lo = f2h(tile[c * 57 + w]);
    unsigned hi = f2h(tile[(c + 1) * 57 + w]);
    *reinterpret_cast<unsigned*>(&dst[w * CIN + c]) = lo | (hi << 16);
  }
  if (threadIdx.x < HW) {
    float s = 0.f;
    for (int c = 0; c < CIN; ++c) s += tile[c * 57 + threadIdx.x];
    xs[(size_t)bh * HW + threadIdx.x] = s;
  }
}

// ---- prep_w: core [COUT][CIN][3][3] f32 -> w_t [COUT][9][CIN] f16 ----
__global__ __launch_bounds__(256) void prep_w(const float* __restrict__ core,
                                              unsigned short* __restrict__ w_t) {
  int i = blockIdx.x * 256 + threadIdx.x;  // < 256*9*128
  int c = i & 127;
  int p = (i >> 7) % 9;
  int m = i / (9 * 128);
  w_t[i] = f2h(core[(size_t)(m * CIN + c) * 9 + p]);
}

// ---- periphery stencil on xs ----
__global__ __launch_bounds__(256) void periph_k(const float* __restrict__ xs,
                                                const float* __restrict__ per,
                                                float* __restrict__ po) {
  int n = blockIdx.x * 256 + threadIdx.x;
  int b = n / HW2, r = n - b * HW2;
  int ho = r / HW, wo = r - ho * HW;
  const float* xb = xs + (size_t)b * HW2;
  const int pdy[16] = {0,0,0,0,0,1,1,2,2,3,3,4,4,4,4,4};
  const int pdx[16] = {0,1,2,3,4,0,4,0,4,0,4,0,1,2,3,4};
  float acc = 0.f;
#pragma unroll
  for (int t = 0; t < 16; ++t) {
    int h = ho + pdy[t] - 2, w = wo + pdx[t] - 2;
    if ((unsigned)h < HW && (unsigned)w < HW) acc += per[t] * xb[h * HW + w];
  }
  po[n] = acc;
}

// ---- implicit-GEMM conv, BM=256 BN=128 BK=32, 2 blocks/CU (cross-block TLP) ----
// 8 waves (4M x 2N), wave tile 64x64 (acc = 64 VGPR -> total <=128 ->
// 16 waves/CU = 2 blocks/CU; their stall phases interleave, m97/m114
// mechanism). Double-buffered LDS 2 x [A 16KB | B 8KB] = 48KB. 36 K-tiles
// (9 taps x 4 c-quarters). Rows are 64B (BK=32): swizzle slot'=slot^((r>>1)&3)
// gives exact 2-way bank aliasing (free) on ds_read_b128; staging uses
// linear LDS dest + inverse-swizzled global source (same involution).
// Counted vmcnt(3) per tile, never 0 in steady state; raw barrier pair.
__global__ __launch_bounds__(512, 4) void gemm_k(const unsigned short* __restrict__ xp,
                                                 const unsigned short* __restrict__ w_t,
                                                 const float* __restrict__ po,
                                                 const float* __restrict__ thresh,
                                                 const float* __restrict__ scale,
                                                 float* __restrict__ out) {
  __shared__ __align__(16) char sMem[2 * 24576];

  const int tid = threadIdx.x;
  const int lane = tid & 63;
  const int wid = tid >> 6;  // 0..7
  const int wm = wid >> 1;   // 0..3 (cout quadrant, 64 couts)
  const int wn = wid & 1;    // 0..1 (pixel half, 64 px)

  // XCD-chunked bijective swizzle: nwg=784=8*98
  const int bid = blockIdx.x;
  const int n0 = ((bid & 7) * 98 + (bid >> 3)) << 7;

  // ---- staging addresses ----
  const int l4 = lane >> 2;  // row within 16-row chunk
  const int ls = lane & 3;   // stored 16B slot within 64B row
  const char* xpc = (const char*)xp;
  const char* wtc = (const char*)w_t;
  // A: chunks 2*wid, 2*wid+1 (rows 32*wid..32*wid+31)
  int aSrc[2];
#pragma unroll
  for (int k = 0; k < 2; ++k) {
    int r = wid * 32 + k * 16 + l4;                 // cout row 0..255
    aSrc[k] = r * 2304 + ((ls ^ ((r >> 1) & 3)) << 4);  // 2304 = 9*128*2B
  }
  const int aDst0 = wid * 2048;  // two 1KB chunks, wave-uniform
  // B: chunk wid (rows 16*wid..16*wid+15)
  int bSrc;
  {
    int r = wid * 16 + l4;  // pixel row 0..127
    int n = n0 + r;
    int b = n / HW2, rr = n - b * HW2;
    int h = rr / HW, w = rr - h * HW;
    bSrc = ((b * PH + h + 1) * PH + (w + 1)) * 256 + ((ls ^ ((r >> 1) & 3)) << 4);
  }
  const int bDst = 16384 + wid * 1024;

  // ---- fragment read offsets (swizzled) ----
  int aro[4], bro[4];
#pragma unroll
  for (int i = 0; i < 4; ++i) {
    int rowA = wm * 64 + i * 16 + (lane & 15);
    aro[i] = rowA * 64 + ((((lane >> 4) ^ (rowA >> 1)) & 3) << 4);
  }
#pragma unroll
  for (int j = 0; j < 4; ++j) {
    int rowB = wn * 64 + j * 16 + (lane & 15);
    bro[j] = 16384 + rowB * 64 + ((((lane >> 4) ^ (rowB >> 1)) & 3) << 4);
  }

  auto STAGE = [&](int buf, int t) {
    const int p = t >> 2;               // tap 0..8
    const int cq = t & 3;               // channel quarter
    const int dy = p / 3 - 1, dx = p - (p / 3) * 3 - 1;
    const int offA = (p << 8) + (cq << 6);
    const int offB = ((dy * PH + dx) << 8) + (cq << 6);
    char* base = sMem + buf * 24576;
    GLD_LDS16(wtc + aSrc[0] + offA, base + aDst0);
    GLD_LDS16(wtc + aSrc[1] + offA, base + aDst0 + 1024);
    GLD_LDS16(xpc + bSrc + offB, base + bDst);
  };

  f32x4 acc[4][4] = {};

  STAGE(0, 0);
  __syncthreads();  // drains stage(0)

  for (int t = 0; t < 36; ++t) {
    const char* base = sMem + (t & 1) * 24576;
    __builtin_amdgcn_s_barrier();  // reads of buf^1 (iter t-1) complete
    if (t < 35) {
      STAGE((t + 1) & 1, t + 1);
      asm volatile("s_waitcnt vmcnt(3)" ::: "memory");  // stage(t) landed
    } else {
      asm volatile("s_waitcnt vmcnt(0)" ::: "memory");
    }
    __builtin_amdgcn_s_barrier();  // everyone's stage(t) landed

    f16x8 bfr[4];
#pragma unroll
    for (int j = 0; j < 4; ++j)
      bfr[j] = *reinterpret_cast<const f16x8*>(base + bro[j]);
#pragma unroll
    for (int i = 0; i < 4; ++i) {
      f16x8 af = *reinterpret_cast<const f16x8*>(base + aro[i]);
      __builtin_amdgcn_s_setprio(1);
#pragma unroll
      for (int j = 0; j < 4; ++j)
        acc[i][j] = __builtin_amdgcn_mfma_f32_16x16x32_f16(af, bfr[j], acc[i][j], 0, 0, 0);
      __builtin_amdgcn_s_setprio(0);
    }
  }

  const float sc = scale[0];
#pragma unroll
  for (int j = 0; j < 4; ++j) {
    int n = n0 + wn * 64 + j * 16 + (lane & 15);
    int b = n / HW2;
    int r = n - b * HW2;  // ho*56+wo
    float pv = po[n];
    float* op = out + (size_t)b * (COUT * HW2) + r;
#pragma unroll
    for (int i = 0; i < 4; ++i) {
      int cl = wm * 64 + i * 16 + ((lane >> 4) << 2);
      f32x4 th = *reinterpret_cast<const f32x4*>(&thresh[cl]);
#pragma unroll
      for (int q = 0; q < 4; ++q) {
        float cv = acc[i][j][q];
        float g = 1.f / (1.f + __expf(-sc * (cv - th[q])));
        op[(size_t)(cl + q) * HW2] = cv + g * pv;
      }
    }
  }
}

extern "C" void kernel_launch(void* const* d_in, const int* in_sizes, int n_in,
                              void* d_out, int out_size, void* d_ws, size_t ws_size,
                              hipStream_t stream) {
  (void)in_sizes; (void)n_in; (void)out_size; (void)ws_size;
  const float* x      = (const float*)d_in[0];
  const float* core   = (const float*)d_in[1];
  const float* per    = (const float*)d_in[2];
  const float* thresh = (const float*)d_in[3];
  const float* scale  = (const float*)d_in[4];
  float* out = (float*)d_out;

  char* ws = (char*)d_ws;
  unsigned short* xp  = (unsigned short*)ws;                  // 32*58*58*128*2 = 27,557,888 B
  unsigned short* w_t = (unsigned short*)(ws + 27557888);     // 589,824 B
  float* xs           = (float*)(ws + 28147712);              // 401,408 B
  float* po           = (float*)(ws + 28549120);              // 401,408 B

  zero_halo<<<(NB * 228 * 16) / 256, 256, 0, stream>>>(xp);
  prep_x<<<NB * HW, 256, 0, stream>>>(x, xp, xs);
  prep_w<<<(COUT * 9 * CIN) / 256, 256, 0, stream>>>(core, w_t);
  periph_k<<<NPIX / 256, 256, 0, stream>>>(xs, per, po);
  gemm_k<<<NPIX / 128, 512, 0, stream>>>(xp, w_t, po, thresh, scale, out);
}

// Round 7
// 120.831 us; speedup vs baseline: 1.0287x; 1.0287x over previous
//
#include <hip/hip_runtime.h>

typedef __attribute__((__ext_vector_type__(8))) _Float16 f16x8;
typedef __attribute__((__ext_vector_type__(4))) float f32x4;
typedef __attribute__((__ext_vector_type__(4))) int i32x4;

#define HW 56
#define HW2 3136
#define CIN 128
#define COUT 256
#define NB 32
#define NPIX 100352  // 32*3136
#define PH 58        // padded spatial dim (1-px halo)

static __device__ __forceinline__ unsigned short f2h(float f) {
  _Float16 h = (_Float16)f;
  return __builtin_bit_cast(unsigned short, h);
}

#define GLD_LDS16(g, l)                                          \
  __builtin_amdgcn_global_load_lds(                              \
      (const __attribute__((address_space(1))) void*)(g),        \
      (__attribute__((address_space(3))) void*)(l), 16, 0, 0)

// ---- prep_x: x NCHW f32 -> x_pad [32][58][58][128] f16 + channel-sum xs;
//      blocks >= NB*HW zero the 1-px halo ----
__global__ __launch_bounds__(256) void prep_x(const float* __restrict__ x,
                                              unsigned short* __restrict__ xp,
                                              float* __restrict__ xs) {
  if (blockIdx.x >= NB * HW) {  // halo-zero blocks
    int t = (blockIdx.x - NB * HW) * 256 + threadIdx.x;  // < 32*228*16
    int ck = t & 15;
    int pi = t >> 4;
    int b = pi / 228, r = pi - b * 228;
    int h, w;
    if (r < 58) { h = 0; w = r; }
    else if (r < 116) { h = 57; w = r - 58; }
    else { int q = r - 116; h = 1 + (q >> 1); w = (q & 1) * 57; }
    size_t off = (((size_t)(b * PH + h) * PH + w) << 8) + (ck << 4);
    *reinterpret_cast<i32x4*>((char*)xp + off) = (i32x4){0, 0, 0, 0};
    return;
  }
  __shared__ float tile[CIN * 57];  // [c][w], stride 57 kills bank conflicts
  const int bh = blockIdx.x;        // b*56 + h
  const float* src = x + (size_t)(bh / HW) * CIN * HW2 + (size_t)(bh % HW) * HW;
  for (int idx = threadIdx.x; idx < CIN * HW; idx += 256) {
    int c = idx / HW, w = idx - c * HW;
    tile[c * 57 + w] = src[(size_t)c * HW2 + w];
  }
  __syncthreads();
  unsigned short* dst =
      xp + (((size_t)(bh / HW) * PH + (bh % HW) + 1) * PH + 1) * CIN;
  for (int idx = threadIdx.x; idx < HW * (CIN / 2); idx += 256) {
    int w = idx >> 6;         // pixel within row
    int c = (idx & 63) << 1;  // channel pair
    unsigned lo = f2h(tile[c * 57 + w]);
    unsigned hi = f2h(tile[(c + 1) * 57 + w]);
    *reinterpret_cast<unsigned*>(&dst[w * CIN + c]) = lo | (hi << 16);
  }
  if (threadIdx.x < HW) {
    float s = 0.f;
    for (int c = 0; c < CIN; ++c) s += tile[c * 57 + threadIdx.x];
    xs[(size_t)bh * HW + threadIdx.x] = s;
  }
}

// ---- prep_w: core [COUT][CIN][3][3] f32 -> w_t [COUT][9][CIN] f16 ----
__global__ __launch_bounds__(256) void prep_w(const float* __restrict__ core,
                                              unsigned short* __restrict__ w_t) {
  int i = blockIdx.x * 256 + threadIdx.x;  // < 256*9*128
  int c = i & 127;
  int p = (i >> 7) % 9;
  int m = i / (9 * 128);
  w_t[i] = f2h(core[(size_t)(m * CIN + c) * 9 + p]);
}

// ---- periphery stencil on xs ----
__global__ __launch_bounds__(256) void periph_k(const float* __restrict__ xs,
                                                const float* __restrict__ per,
                                                float* __restrict__ po) {
  int n = blockIdx.x * 256 + threadIdx.x;
  int b = n / HW2, r = n - b * HW2;
  int ho = r / HW, wo = r - ho * HW;
  const float* xb = xs + (size_t)b * HW2;
  const int pdy[16] = {0,0,0,0,0,1,1,2,2,3,3,4,4,4,4,4};
  const int pdx[16] = {0,1,2,3,4,0,4,0,4,0,4,0,1,2,3,4};
  float acc = 0.f;
#pragma unroll
  for (int t = 0; t < 16; ++t) {
    int h = ho + pdy[t] - 2, w = wo + pdx[t] - 2;
    if ((unsigned)h < HW && (unsigned)w < HW) acc += per[t] * xb[h * HW + w];
  }
  po[n] = acc;
}

// ---- implicit-GEMM conv: BM=256 BN=128 BK=32, 4 waves (2M x 2N),
// wave tile 128x64 (42.7 FLOP/LDS-byte, above the ~40 balance point),
// 3 blocks/CU target (VGPR<=170 via __launch_bounds__(256,3); LDS 48KB x3
// = 144KB). Cross-block TLP fills each block's stage/barrier stalls (m114).
// Counted vmcnt(6) per K-tile (never 0 in steady state); raw barrier pair;
// 2-way-free LDS swizzle; XCD-chunked block swizzle. 36 K-tiles.
__global__ __launch_bounds__(256, 3) void gemm_k(const unsigned short* __restrict__ xp,
                                                 const unsigned short* __restrict__ w_t,
                                                 const float* __restrict__ po,
                                                 const float* __restrict__ thresh,
                                                 const float* __restrict__ scale,
                                                 float* __restrict__ out) {
  __shared__ __align__(16) char sMem[2 * 24576];  // [A 16KB | B 8KB] x 2

  const int tid = threadIdx.x;
  const int lane = tid & 63;
  const int wid = tid >> 6;  // 0..3
  const int wm = wid >> 1;   // 0..1 (cout half, 128 couts)
  const int wn = wid & 1;    // 0..1 (pixel half, 64 px)

  // XCD-chunked bijective swizzle: nwg=784=8*98
  const int bid = blockIdx.x;
  const int n0 = ((bid & 7) * 98 + (bid >> 3)) << 7;

  // ---- staging addresses (linear LDS dest + inverse-swizzled global src) ----
  const int l4 = lane >> 2;  // row within 16-row chunk
  const int ls = lane & 3;   // 16B slot within 64B row
  const int sw = (ls ^ ((l4 >> 1) & 3)) << 4;  // (row>>1)&3 == (l4>>1)&3 for all chunks
  const char* xpc = (const char*)xp;
  const char* wtc = (const char*)w_t;
  // A: wave wid stages chunks {wid+4k}, rows (wid+4k)*16+l4, k=0..3
  const int aSrc0 = (wid * 16 + l4) * 2304 + sw;  // +k*147456 (=64 rows*2304B)
  // B: wave wid stages chunks {wid, wid+4}, pixel rows wid*16+l4 (+64)
  int bSrc[2];
#pragma unroll
  for (int k = 0; k < 2; ++k) {
    int n = n0 + wid * 16 + k * 64 + l4;
    int b = n / HW2, rr = n - b * HW2;
    int h = rr / HW, w = rr - h * HW;
    bSrc[k] = ((b * PH + h + 1) * PH + (w + 1)) * 256 + sw;
  }

  // ---- fragment read offsets (swizzled; +i*1024 walks 16-row steps) ----
  const int rowA0 = wm * 128 + (lane & 15);
  const int aro0 = rowA0 * 64 + ((((lane >> 4) ^ (rowA0 >> 1)) & 3) << 4);
  const int rowB0 = wn * 64 + (lane & 15);
  const int bro0 = 16384 + rowB0 * 64 + ((((lane >> 4) ^ (rowB0 >> 1)) & 3) << 4);

  auto STAGE = [&](int buf, int t) {
    const int p = t >> 2;  // tap 0..8
    const int cq = t & 3;  // channel quarter
    const int dy = p / 3 - 1, dx = p - (p / 3) * 3 - 1;
    const int offA = (p << 8) + (cq << 6);
    const int offB = ((dy * PH + dx) << 8) + (cq << 6);
    char* base = sMem + buf * 24576;
#pragma unroll
    for (int k = 0; k < 4; ++k)
      GLD_LDS16(wtc + aSrc0 + k * 147456 + offA, base + (wid + 4 * k) * 1024);
#pragma unroll
    for (int k = 0; k < 2; ++k)
      GLD_LDS16(xpc + bSrc[k] + offB, base + 16384 + (wid + 4 * k) * 1024);
  };

  f32x4 acc[8][4] = {};

  STAGE(0, 0);
  __syncthreads();  // drains stage(0)

  for (int t = 0; t < 36; ++t) {
    const char* base = sMem + (t & 1) * 24576;
    __builtin_amdgcn_s_barrier();  // reads of buf (iter t-2) complete everywhere
    if (t < 35) {
      STAGE((t + 1) & 1, t + 1);
      asm volatile("s_waitcnt vmcnt(6)" ::: "memory");  // stage(t) landed
    } else {
      asm volatile("s_waitcnt vmcnt(0)" ::: "memory");
    }
    __builtin_amdgcn_s_barrier();  // everyone's stage(t) landed

    f16x8 bfr[4];
#pragma unroll
    for (int j = 0; j < 4; ++j)
      bfr[j] = *reinterpret_cast<const f16x8*>(base + bro0 + j * 1024);
#pragma unroll
    for (int i = 0; i < 8; ++i) {
      f16x8 af = *reinterpret_cast<const f16x8*>(base + aro0 + i * 1024);
      __builtin_amdgcn_s_setprio(1);
#pragma unroll
      for (int j = 0; j < 4; ++j)
        acc[i][j] = __builtin_amdgcn_mfma_f32_16x16x32_f16(af, bfr[j], acc[i][j], 0, 0, 0);
      __builtin_amdgcn_s_setprio(0);
    }
  }

  const float sc = scale[0];
#pragma unroll
  for (int j = 0; j < 4; ++j) {
    int n = n0 + wn * 64 + j * 16 + (lane & 15);
    int b = n / HW2;
    int r = n - b * HW2;  // ho*56+wo
    float pv = po[n];
    float* op = out + (size_t)b * (COUT * HW2) + r;
#pragma unroll
    for (int i = 0; i < 8; ++i) {
      int cl = wm * 128 + i * 16 + ((lane >> 4) << 2);
      f32x4 th = *reinterpret_cast<const f32x4*>(&thresh[cl]);
#pragma unroll
      for (int q = 0; q < 4; ++q) {
        float cv = acc[i][j][q];
        float g = 1.f / (1.f + __expf(-sc * (cv - th[q])));
        op[(size_t)(cl + q) * HW2] = cv + g * pv;
      }
    }
  }
}

extern "C" void kernel_launch(void* const* d_in, const int* in_sizes, int n_in,
                              void* d_out, int out_size, void* d_ws, size_t ws_size,
                              hipStream_t stream) {
  (void)in_sizes; (void)n_in; (void)out_size; (void)ws_size;
  const float* x      = (const float*)d_in[0];
  const float* core   = (const float*)d_in[1];
  const float* per    = (const float*)d_in[2];
  const float* thresh = (const float*)d_in[3];
  const float* scale  = (const float*)d_in[4];
  float* out = (float*)d_out;

  char* ws = (char*)d_ws;
  unsigned short* xp  = (unsigned short*)ws;                  // 32*58*58*128*2 = 27,557,888 B
  unsigned short* w_t = (unsigned short*)(ws + 27557888);     // 589,824 B
  float* xs           = (float*)(ws + 28147712);              // 401,408 B
  float* po           = (float*)(ws + 28549120);              // 401,408 B

  prep_x<<<NB * HW + 456, 256, 0, stream>>>(x, xp, xs);  // +456 halo blocks
  prep_w<<<(COUT * 9 * CIN) / 256, 256, 0, stream>>>(core, w_t);
  periph_k<<<NPIX / 256, 256, 0, stream>>>(xs, per, po);
  gemm_k<<<NPIX / 128, 256, 0, stream>>>(xp, w_t, po, thresh, scale, out);
}